// Round 7
// baseline (6526.846 us; speedup 1.0000x reference)
//
#include <hip/hip_runtime.h>
#include <hip/hip_bf16.h>

typedef __attribute__((ext_vector_type(8))) short s16x8;
typedef __attribute__((ext_vector_type(4))) float f32x4;

#define B_    8
#define H_    224
#define W_    224
#define S_    196
#define D_    768
#define HW    50176          // 224*224
#define NPIX  401408         // B_*HW
#define SL    1792           // slice pixels: 1792*28 = 50176 = HW exactly; 1792/128 = 14
#define NSL   224            // NPIX / SL

__device__ inline float bf2f(unsigned short u) {
    return __uint_as_float(((unsigned)u) << 16);
}
__device__ inline unsigned short f2bf(float f) {
    unsigned u = __float_as_uint(f);
    u = (u + 0x7FFFu + ((u >> 16) & 1u)) >> 16;
    return (unsigned short)u;
}

// ---------------- conv1 pass 1: raw conv -> BN1 batch stats only ----------------
__global__ __launch_bounds__(256) void k_conv1s(const float* __restrict__ img,
        const float* __restrict__ w, const float* __restrict__ bias,
        float* __restrict__ st) {
    __shared__ float lw[64 * 27];
    __shared__ float ls[256], lq[256];
    int t = threadIdx.x;
    for (int i = t; i < 64 * 27; i += 256) lw[i] = w[i];
    __syncthreads();
    int oc = t & 63;
    float bv = bias[oc];
    float s = 0.f, q = 0.f;
    for (int pg = blockIdx.x; pg < NPIX / 4; pg += 2048) {
        int p = pg * 4 + (t >> 6);
        int b = p / HW; int rem = p - b * HW;
        int y = rem / W_; int x = rem - y * W_;
        const float* ib = img + (long)b * 3 * HW;
        float acc = bv;
        #pragma unroll
        for (int ic = 0; ic < 3; ++ic) {
            #pragma unroll
            for (int ky = 0; ky < 3; ++ky) {
                int yy = y + ky - 1;
                if (yy < 0 || yy >= H_) continue;
                #pragma unroll
                for (int kx = 0; kx < 3; ++kx) {
                    int xx = x + kx - 1;
                    if (xx < 0 || xx >= W_) continue;
                    acc += ib[(ic * H_ + yy) * W_ + xx] * lw[oc * 27 + ic * 9 + ky * 3 + kx];
                }
            }
        }
        s += acc; q += acc * acc;
    }
    ls[t] = s; lq[t] = q;
    __syncthreads();
    if (t < 64) {
        atomicAdd(&st[t],      ls[t] + ls[t + 64] + ls[t + 128] + ls[t + 192]);
        atomicAdd(&st[64 + t], lq[t] + lq[t + 64] + lq[t + 128] + lq[t + 192]);
    }
}

__global__ void k_fin1(const float* __restrict__ st, const float* __restrict__ g,
        const float* __restrict__ bta, float* __restrict__ s1t1) {
    int c = threadIdx.x;
    if (c >= 64) return;
    float n = (float)NPIX;
    float mean = st[c] / n;
    float var  = st[64 + c] / n - mean * mean;
    float sc = g[c] * rsqrtf(var + 1e-5f);
    s1t1[c] = sc;
    s1t1[64 + c] = bta[c] - mean * sc;
}

// ---------------- conv1 pass 2: recompute + BN1 + ReLU -> UNPADDED NHWC bf16 ----------------
__global__ __launch_bounds__(256) void k_conv1a(const float* __restrict__ img,
        const float* __restrict__ w, const float* __restrict__ bias,
        const float* __restrict__ s1t1, unsigned short* __restrict__ x2) {
    __shared__ float lw[64 * 27];
    int t = threadIdx.x;
    for (int i = t; i < 64 * 27; i += 256) lw[i] = w[i];
    __syncthreads();
    int oc = t & 63;
    int p  = blockIdx.x * 4 + (t >> 6);
    int b = p / HW; int rem = p - b * HW;
    int y = rem / W_; int x = rem - y * W_;
    const float* ib = img + (long)b * 3 * HW;
    float acc = bias[oc];
    #pragma unroll
    for (int ic = 0; ic < 3; ++ic) {
        #pragma unroll
        for (int ky = 0; ky < 3; ++ky) {
            int yy = y + ky - 1;
            if (yy < 0 || yy >= H_) continue;
            #pragma unroll
            for (int kx = 0; kx < 3; ++kx) {
                int xx = x + kx - 1;
                if (xx < 0 || xx >= W_) continue;
                acc += ib[(ic * H_ + yy) * W_ + xx] * lw[oc * 27 + ic * 9 + ky * 3 + kx];
            }
        }
    }
    float v = s1t1[oc] * acc + s1t1[64 + oc];
    v = v > 0.f ? v : 0.f;
    x2[(long)p * 64 + oc] = f2bf(v);
}

// ---------------- weight prep: Bm [768][576] bf16, k = tap*64 + ic ----------------
__global__ __launch_bounds__(256) void k_prep(const float* __restrict__ w2,
        unsigned short* __restrict__ Bm) {
    int i = blockIdx.x * 256 + threadIdx.x;
    if (i < 768 * 576) {
        int oc = i / 576, k = i - oc * 576;
        int tap = k >> 6, ic = k & 63;
        Bm[i] = f2bf(w2[(oc * 64 + ic) * 9 + tap]);
    }
}

// ---------------- conv2 as implicit GEMM (MFMA): C[m][oc] = sum_k A[m][k]*Bm[oc][k] + b ----
template<int STORE, int STATS>
__global__ __launch_bounds__(256) void k_conv2(const unsigned short* __restrict__ x2,
        const unsigned short* __restrict__ Bm, const float* __restrict__ cb,
        unsigned short* __restrict__ C, float* __restrict__ st2, int m_base) {
    __shared__ short lA[128 * 32];
    __shared__ short lB[128 * 32];
    int t = threadIdx.x;
    int mt0 = blockIdx.x * 128;       // chunk-local tile row
    int m0  = m_base + mt0;           // global pixel row
    int oc0 = blockIdx.y * 128;

    int r  = t >> 1;
    int e0 = (t & 1) * 16;
    int m = m0 + r;
    int b = m / HW; int rem = m - b * HW;
    int y = rem / W_; int x = rem - y * W_;
    const unsigned short* Pb = x2 + (long)b * HW * 64;
    const unsigned short* Q  = Bm + (long)(oc0 + r) * 576;

    int lane = t & 63;
    int w = t >> 6;
    int wm = w >> 1, wn = w & 1;
    int l15 = lane & 15;
    int koff = (lane >> 4) * 8;

    f32x4 acc[4][4];
    #pragma unroll
    for (int i = 0; i < 4; ++i)
        #pragma unroll
        for (int j = 0; j < 4; ++j) acc[i][j] = (f32x4){0.f, 0.f, 0.f, 0.f};

    for (int s = 0; s < 18; ++s) {
        int tap = s >> 1;
        int ty = tap / 3, tx = tap - ty * 3;
        int yy = y + 2 * ty - 2;
        int xx = x + 2 * tx - 2;
        float4 a0 = {0.f, 0.f, 0.f, 0.f}, a1 = {0.f, 0.f, 0.f, 0.f};
        if ((unsigned)yy < (unsigned)H_ && (unsigned)xx < (unsigned)W_) {
            const unsigned short* src = Pb + ((long)yy * W_ + xx) * 64 + (s & 1) * 32 + e0;
            a0 = *(const float4*)src;
            a1 = *(const float4*)(src + 8);
        }
        float4 b0 = *(const float4*)(Q + s * 32 + e0);
        float4 b1 = *(const float4*)(Q + s * 32 + e0 + 8);
        *(float4*)&lA[r * 32 + e0]     = a0;
        *(float4*)&lA[r * 32 + e0 + 8] = a1;
        *(float4*)&lB[r * 32 + e0]     = b0;
        *(float4*)&lB[r * 32 + e0 + 8] = b1;
        __syncthreads();
        s16x8 af[4], bf[4];
        #pragma unroll
        for (int i = 0; i < 4; ++i)
            af[i] = *(const s16x8*)&lA[(wm * 64 + i * 16 + l15) * 32 + koff];
        #pragma unroll
        for (int j = 0; j < 4; ++j)
            bf[j] = *(const s16x8*)&lB[(wn * 64 + j * 16 + l15) * 32 + koff];
        #pragma unroll
        for (int i = 0; i < 4; ++i)
            #pragma unroll
            for (int j = 0; j < 4; ++j)
                acc[i][j] = __builtin_amdgcn_mfma_f32_16x16x32_bf16(af[i], bf[j], acc[i][j], 0, 0, 0);
        __syncthreads();
    }

    int lrow = mt0 + wm * 64 + (lane >> 4) * 4;   // chunk-local output row base
    #pragma unroll
    for (int j = 0; j < 4; ++j) {
        int col = oc0 + wn * 64 + j * 16 + l15;
        float cbv = cb[col];
        float sp = 0.f, sq = 0.f;
        #pragma unroll
        for (int i = 0; i < 4; ++i) {
            #pragma unroll
            for (int q = 0; q < 4; ++q) {
                float v = acc[i][j][q] + cbv;
                if (STORE) C[(long)(lrow + i * 16 + q) * 768 + col] = f2bf(v);
                if (STATS) { sp += v; sq += v * v; }
            }
        }
        if (STATS) {
            sp += __shfl_xor(sp, 16); sp += __shfl_xor(sp, 32);
            sq += __shfl_xor(sq, 16); sq += __shfl_xor(sq, 32);
            if (lane < 16) {
                atomicAdd(&st2[col], sp);
                atomicAdd(&st2[768 + col], sq);
            }
        }
    }
}

__global__ void k_fin2(const float* __restrict__ st, const float* __restrict__ g,
        const float* __restrict__ bta, float* __restrict__ s2t2) {
    int c = blockIdx.x * 256 + threadIdx.x;
    if (c >= 768) return;
    float n = (float)NPIX;
    float mean = st[c] / n;
    float var  = st[768 + c] / n - mean * mean;
    float sc = g[c] * rsqrtf(var + 1e-5f);
    s2t2[c] = sc;
    s2t2[768 + c] = bta[c] - mean * sc;
}

// ---------------- pooling: grid (n_slices, 24) of 32-channel blocks ----------
__global__ __launch_bounds__(256) void k_pool2(const unsigned short* __restrict__ Cc,
        const int* __restrict__ seg, const float* __restrict__ s2t2,
        float* __restrict__ msum, float* __restrict__ mmax, int base_pix) {
    __shared__ float    ssum[S_ * 32];
    __shared__ unsigned smax[S_ * 32];
    int t = threadIdx.x;
    for (int i = t; i < S_ * 32; i += 256) { ssum[i] = 0.f; smax[i] = 0u; }
    __syncthreads();
    int ch0 = blockIdx.y * 32;
    int cl  = t & 31;                 // channel within block
    int ch  = ch0 + cl;
    int gp0 = base_pix + blockIdx.x * SL;
    float sc = s2t2[ch], sh = s2t2[768 + ch];
    const unsigned short* Cb = Cc + (long)blockIdx.x * SL * 768;   // chunk-local rows
    const int* sg = seg + gp0;
    for (int p = (t >> 5); p < SL; p += 8) {
        int s = sg[p];
        float v = sc * bf2f(Cb[(long)p * 768 + ch]) + sh;
        v = v > 0.f ? v : 0.f;
        atomicAdd(&ssum[s * 32 + cl], v);
        atomicMax(&smax[s * 32 + cl], __float_as_uint(v));
    }
    __syncthreads();
    int b = gp0 / HW;                 // exact: SL | HW
    for (int i = t; i < S_ * 32; i += 256) {
        int s = i >> 5; int cc = i & 31;
        long o = ((long)(b * S_ + s)) * 768 + ch0 + cc;
        atomicAdd(&msum[o], ssum[i]);
        atomicMax((unsigned*)&mmax[o], smax[i]);
    }
}

// ---------------- geometry: global atomics per pixel ----------------
__global__ void k_ginit(int* __restrict__ counts, int* __restrict__ bbox) {
    int i = blockIdx.x * 256 + threadIdx.x;
    if (i < B_ * S_) {
        counts[i] = 0;
        bbox[i * 4 + 0] = 1 << 29;  bbox[i * 4 + 1] = -1;
        bbox[i * 4 + 2] = 1 << 29;  bbox[i * 4 + 3] = -1;
    }
}

__global__ void k_geom2(const int* __restrict__ seg, int* __restrict__ counts,
        int* __restrict__ bbox) {
    int p = blockIdx.x * 256 + threadIdx.x;   // < NPIX
    int b = p / HW; int rem = p - b * HW;
    int y = rem / W_; int x = rem - y * W_;
    int gs = b * S_ + seg[p];
    atomicAdd(&counts[gs], 1);
    atomicMin(&bbox[gs * 4 + 0], x); atomicMax(&bbox[gs * 4 + 1], x);
    atomicMin(&bbox[gs * 4 + 2], y); atomicMax(&bbox[gs * 4 + 3], y);
}

// ---------------- head: one block per (batch,segment) token -> F32 output ----------------
__global__ __launch_bounds__(256) void k_out2(
        const float* __restrict__ msum, const float* __restrict__ mmax,
        const int* __restrict__ counts, const int* __restrict__ bbox,
        const float* __restrict__ cent, const float* __restrict__ fw,
        const float* __restrict__ sw2, const float* __restrict__ fb,
        const float* __restrict__ sw1, const float* __restrict__ sb1,
        const float* __restrict__ sb2, const float* __restrict__ pw,
        const float* __restrict__ pb, float* __restrict__ out) {
    __shared__ float emb[1536];
    __shared__ float hid[768];
    int gs = blockIdx.x;              // 0 .. B*S-1
    int t = threadIdx.x;
    int cnt = counts[gs];
    float cntf = (float)cnt;
    float inv = 1.f / fmaxf(cntf, 1.f);
    float bwf = 1.f, bhf = 1.f;
    if (cnt > 0) {
        bwf = (float)(bbox[gs * 4 + 1] - bbox[gs * 4 + 0] + 1);
        bhf = (float)(bbox[gs * 4 + 3] - bbox[gs * 4 + 2] + 1);
    }
    float asp = bwf / bhf;            // bw,bh >= 1 so the 1e-6 clip is inert
    for (int k = t; k < 768; k += 256) {
        emb[k]       = msum[(long)gs * 768 + k] * inv;
        emb[768 + k] = mmax[(long)gs * 768 + k];
        float h = cntf * sw1[2 * k] + asp * sw1[2 * k + 1] + sb1[k];
        hid[k] = h > 0.f ? h : 0.f;
    }
    __syncthreads();
    float cx = cent[gs * 2]     * (1.f / (float)W_);
    float cy = cent[gs * 2 + 1] * (1.f / (float)H_);
    for (int rr = 0; rr < 3; ++rr) {
        int d = t + rr * 256;
        float acc = fb[d] + sb2[d] + pb[d] + cx * pw[d * 2] + cy * pw[d * 2 + 1];
        const float* fwr = fw + (long)d * 1536;
        #pragma unroll 4
        for (int k = 0; k < 1536; ++k) acc += emb[k] * fwr[k];
        const float* swr = sw2 + (long)d * 768;
        #pragma unroll 4
        for (int k = 0; k < 768; ++k) acc += hid[k] * swr[k];
        out[(long)gs * 768 + d] = acc;      // F32 output — reference output dtype
    }
}

extern "C" void kernel_launch(void* const* d_in, const int* in_sizes, int n_in,
                              void* d_out, int out_size, void* d_ws, size_t ws_size,
                              hipStream_t stream) {
    const float* img  = (const float*)d_in[0];
    const int*   seg  = (const int*)  d_in[1];
    const float* cent = (const float*)d_in[2];
    const float* c1w  = (const float*)d_in[3];
    const float* c1b  = (const float*)d_in[4];
    const float* bn1g = (const float*)d_in[5];
    const float* bn1b = (const float*)d_in[6];
    const float* c2w  = (const float*)d_in[7];
    const float* c2b  = (const float*)d_in[8];
    const float* bn2g = (const float*)d_in[9];
    const float* bn2b = (const float*)d_in[10];
    const float* fw   = (const float*)d_in[11];
    const float* fbv  = (const float*)d_in[12];
    const float* pw   = (const float*)d_in[13];
    const float* pb   = (const float*)d_in[14];
    const float* sw1  = (const float*)d_in[15];
    const float* sb1  = (const float*)d_in[16];
    const float* sw2  = (const float*)d_in[17];
    const float* sb2  = (const float*)d_in[18];

    char* base = (char*)d_ws;
    size_t used = 0;
    auto alloc = [&](size_t bytes) {
        char* p = base + used;
        used += (bytes + 255) & ~(size_t)255;
        return p;
    };
    unsigned short* x2 = (unsigned short*)alloc((size_t)NPIX * 64 * 2);     // 51.4 MB
    unsigned short* Bm = (unsigned short*)alloc((size_t)768 * 576 * 2);     // 0.88 MB
    float* st1  = (float*)alloc(128 * 4);
    float* s1t1 = (float*)alloc(128 * 4);
    float* st2  = (float*)alloc(1536 * 4);
    float* s2t2 = (float*)alloc(1536 * 4);
    float* msum = (float*)alloc((size_t)B_ * S_ * 768 * 4);                 // 4.82 MB
    float* mmax = (float*)alloc((size_t)B_ * S_ * 768 * 4);                 // 4.82 MB
    int* counts = (int*)alloc(B_ * S_ * 4);
    int* bbox   = (int*)alloc(B_ * S_ * 16);
    const size_t UNIT_BYTES = (size_t)SL * 768 * 2;   // 2.75 MB per slice
    unsigned short* Cc = (unsigned short*)(base + used);
    long units = 0;
    if (ws_size > used) units = (long)((ws_size - used) / UNIT_BYTES);
    if (units > NSL) units = NSL;
    if (units < 1)  units = 1;

    hipMemsetAsync(st1, 0, 128 * 4, stream);
    hipMemsetAsync(st2, 0, 1536 * 4, stream);
    hipMemsetAsync(msum, 0, (size_t)B_ * S_ * 768 * 4, stream);
    hipMemsetAsync(mmax, 0, (size_t)B_ * S_ * 768 * 4, stream);

    k_conv1s<<<2048, 256, 0, stream>>>(img, c1w, c1b, st1);
    k_fin1<<<1, 64, 0, stream>>>(st1, bn1g, bn1b, s1t1);
    k_conv1a<<<NPIX / 4, 256, 0, stream>>>(img, c1w, c1b, s1t1, x2);
    k_prep<<<(768 * 576) / 256, 256, 0, stream>>>(c2w, Bm);

    if (units >= NSL) {
        dim3 g2(NPIX / 128, 6);
        k_conv2<1, 1><<<g2, 256, 0, stream>>>(x2, Bm, c2b, Cc, st2, 0);
        k_fin2<<<3, 256, 0, stream>>>(st2, bn2g, bn2b, s2t2);
        dim3 gp(NSL, 24);
        k_pool2<<<gp, 256, 0, stream>>>(Cc, seg, s2t2, msum, mmax, 0);
    } else {
        dim3 g2(NPIX / 128, 6);
        k_conv2<0, 1><<<g2, 256, 0, stream>>>(x2, Bm, c2b, Cc, st2, 0);
        k_fin2<<<3, 256, 0, stream>>>(st2, bn2g, bn2b, s2t2);
        for (long u = 0; u < NSL; u += units) {
            long nu = (NSL - u < units) ? (NSL - u) : units;
            dim3 gc((unsigned)(nu * (SL / 128)), 6);
            k_conv2<1, 0><<<gc, 256, 0, stream>>>(x2, Bm, c2b, Cc, st2, (int)(u * SL));
            dim3 gp((unsigned)nu, 24);
            k_pool2<<<gp, 256, 0, stream>>>(Cc, seg, s2t2, msum, mmax, (int)(u * SL));
        }
    }

    k_ginit<<<(B_ * S_ + 255) / 256, 256, 0, stream>>>(counts, bbox);
    k_geom2<<<NPIX / 256, 256, 0, stream>>>(seg, counts, bbox);
    k_out2<<<B_ * S_, 256, 0, stream>>>(msum, mmax, counts, bbox, cent, fw, sw2,
                                        fbv, sw1, sb1, sb2, pw, pb,
                                        (float*)d_out);
    (void)in_sizes; (void)n_in; (void)out_size;
}

// Round 8
// 4031.142 us; speedup vs baseline: 1.6191x; 1.6191x over previous
//
#include <hip/hip_runtime.h>
#include <hip/hip_bf16.h>

typedef __attribute__((ext_vector_type(8))) short s16x8;
typedef __attribute__((ext_vector_type(4))) float f32x4;

#define B_    8
#define H_    224
#define W_    224
#define S_    196
#define D_    768
#define HW    50176          // 224*224
#define NPIX  401408         // B_*HW
#define SL    1792           // slice pixels: 1792*28 = 50176 = HW exactly; 1792/128 = 14
#define NSL   224            // NPIX / SL

__device__ inline float bf2f(unsigned short u) {
    return __uint_as_float(((unsigned)u) << 16);
}
__device__ inline unsigned short f2bf(float f) {
    unsigned u = __float_as_uint(f);
    u = (u + 0x7FFFu + ((u >> 16) & 1u)) >> 16;
    return (unsigned short)u;
}

// ---------------- conv1 pass 1: raw conv -> BN1 batch stats only ----------------
__global__ __launch_bounds__(256) void k_conv1s(const float* __restrict__ img,
        const float* __restrict__ w, const float* __restrict__ bias,
        float* __restrict__ st) {
    __shared__ float lw[64 * 27];
    __shared__ float ls[256], lq[256];
    int t = threadIdx.x;
    for (int i = t; i < 64 * 27; i += 256) lw[i] = w[i];
    __syncthreads();
    int oc = t & 63;
    float bv = bias[oc];
    float s = 0.f, q = 0.f;
    for (int pg = blockIdx.x; pg < NPIX / 4; pg += 2048) {
        int p = pg * 4 + (t >> 6);
        int b = p / HW; int rem = p - b * HW;
        int y = rem / W_; int x = rem - y * W_;
        const float* ib = img + (long)b * 3 * HW;
        float acc = bv;
        #pragma unroll
        for (int ic = 0; ic < 3; ++ic) {
            #pragma unroll
            for (int ky = 0; ky < 3; ++ky) {
                int yy = y + ky - 1;
                if (yy < 0 || yy >= H_) continue;
                #pragma unroll
                for (int kx = 0; kx < 3; ++kx) {
                    int xx = x + kx - 1;
                    if (xx < 0 || xx >= W_) continue;
                    acc += ib[(ic * H_ + yy) * W_ + xx] * lw[oc * 27 + ic * 9 + ky * 3 + kx];
                }
            }
        }
        s += acc; q += acc * acc;
    }
    ls[t] = s; lq[t] = q;
    __syncthreads();
    if (t < 64) {
        atomicAdd(&st[t],      ls[t] + ls[t + 64] + ls[t + 128] + ls[t + 192]);
        atomicAdd(&st[64 + t], lq[t] + lq[t + 64] + lq[t + 128] + lq[t + 192]);
    }
}

__global__ void k_fin1(const float* __restrict__ st, const float* __restrict__ g,
        const float* __restrict__ bta, float* __restrict__ s1t1) {
    int c = threadIdx.x;
    if (c >= 64) return;
    float n = (float)NPIX;
    float mean = st[c] / n;
    float var  = st[64 + c] / n - mean * mean;
    float sc = g[c] * rsqrtf(var + 1e-5f);
    s1t1[c] = sc;
    s1t1[64 + c] = bta[c] - mean * sc;
}

// ---------------- conv1 pass 2: recompute + BN1 + ReLU -> UNPADDED NHWC bf16 ----------------
__global__ __launch_bounds__(256) void k_conv1a(const float* __restrict__ img,
        const float* __restrict__ w, const float* __restrict__ bias,
        const float* __restrict__ s1t1, unsigned short* __restrict__ x2) {
    __shared__ float lw[64 * 27];
    int t = threadIdx.x;
    for (int i = t; i < 64 * 27; i += 256) lw[i] = w[i];
    __syncthreads();
    int oc = t & 63;
    int p  = blockIdx.x * 4 + (t >> 6);
    int b = p / HW; int rem = p - b * HW;
    int y = rem / W_; int x = rem - y * W_;
    const float* ib = img + (long)b * 3 * HW;
    float acc = bias[oc];
    #pragma unroll
    for (int ic = 0; ic < 3; ++ic) {
        #pragma unroll
        for (int ky = 0; ky < 3; ++ky) {
            int yy = y + ky - 1;
            if (yy < 0 || yy >= H_) continue;
            #pragma unroll
            for (int kx = 0; kx < 3; ++kx) {
                int xx = x + kx - 1;
                if (xx < 0 || xx >= W_) continue;
                acc += ib[(ic * H_ + yy) * W_ + xx] * lw[oc * 27 + ic * 9 + ky * 3 + kx];
            }
        }
    }
    float v = s1t1[oc] * acc + s1t1[64 + oc];
    v = v > 0.f ? v : 0.f;
    x2[(long)p * 64 + oc] = f2bf(v);
}

// ---------------- weight prep: Bm [768][576] bf16 + transposed f32 head weights ----------
__global__ __launch_bounds__(256) void k_prep(const float* __restrict__ w2,
        const float* __restrict__ fw, const float* __restrict__ sw2,
        unsigned short* __restrict__ Bm, float* __restrict__ fwt, float* __restrict__ swt) {
    int i = blockIdx.x * 256 + threadIdx.x;
    if (i < 768 * 576) {
        int oc = i / 576, k = i - oc * 576;
        int tap = k >> 6, ic = k & 63;
        Bm[i] = f2bf(w2[(oc * 64 + ic) * 9 + tap]);
    }
    if (i < 1536 * 768) {          // fwt[k][d] = fw[d][k]
        int k = i / 768, d = i - k * 768;
        fwt[i] = fw[(long)d * 1536 + k];
    }
    if (i < 768 * 768) {           // swt[k][d] = sw2[d][k]
        int k = i / 768, d = i - k * 768;
        swt[i] = sw2[(long)d * 768 + k];
    }
}

// ---------------- conv2 as implicit GEMM (MFMA): C[m][oc] = sum_k A[m][k]*Bm[oc][k] + b ----
template<int STORE, int STATS>
__global__ __launch_bounds__(256) void k_conv2(const unsigned short* __restrict__ x2,
        const unsigned short* __restrict__ Bm, const float* __restrict__ cb,
        unsigned short* __restrict__ C, float* __restrict__ st2, int m_base) {
    __shared__ short lA[128 * 32];
    __shared__ short lB[128 * 32];
    int t = threadIdx.x;
    int mt0 = blockIdx.x * 128;       // chunk-local tile row
    int m0  = m_base + mt0;           // global pixel row
    int oc0 = blockIdx.y * 128;

    int r  = t >> 1;
    int e0 = (t & 1) * 16;
    int m = m0 + r;
    int b = m / HW; int rem = m - b * HW;
    int y = rem / W_; int x = rem - y * W_;
    const unsigned short* Pb = x2 + (long)b * HW * 64;
    const unsigned short* Q  = Bm + (long)(oc0 + r) * 576;

    int lane = t & 63;
    int w = t >> 6;
    int wm = w >> 1, wn = w & 1;
    int l15 = lane & 15;
    int koff = (lane >> 4) * 8;

    f32x4 acc[4][4];
    #pragma unroll
    for (int i = 0; i < 4; ++i)
        #pragma unroll
        for (int j = 0; j < 4; ++j) acc[i][j] = (f32x4){0.f, 0.f, 0.f, 0.f};

    for (int s = 0; s < 18; ++s) {
        int tap = s >> 1;
        int ty = tap / 3, tx = tap - ty * 3;
        int yy = y + 2 * ty - 2;
        int xx = x + 2 * tx - 2;
        float4 a0 = {0.f, 0.f, 0.f, 0.f}, a1 = {0.f, 0.f, 0.f, 0.f};
        if ((unsigned)yy < (unsigned)H_ && (unsigned)xx < (unsigned)W_) {
            const unsigned short* src = Pb + ((long)yy * W_ + xx) * 64 + (s & 1) * 32 + e0;
            a0 = *(const float4*)src;
            a1 = *(const float4*)(src + 8);
        }
        float4 b0 = *(const float4*)(Q + s * 32 + e0);
        float4 b1 = *(const float4*)(Q + s * 32 + e0 + 8);
        *(float4*)&lA[r * 32 + e0]     = a0;
        *(float4*)&lA[r * 32 + e0 + 8] = a1;
        *(float4*)&lB[r * 32 + e0]     = b0;
        *(float4*)&lB[r * 32 + e0 + 8] = b1;
        __syncthreads();
        s16x8 af[4], bf[4];
        #pragma unroll
        for (int i = 0; i < 4; ++i)
            af[i] = *(const s16x8*)&lA[(wm * 64 + i * 16 + l15) * 32 + koff];
        #pragma unroll
        for (int j = 0; j < 4; ++j)
            bf[j] = *(const s16x8*)&lB[(wn * 64 + j * 16 + l15) * 32 + koff];
        #pragma unroll
        for (int i = 0; i < 4; ++i)
            #pragma unroll
            for (int j = 0; j < 4; ++j)
                acc[i][j] = __builtin_amdgcn_mfma_f32_16x16x32_bf16(af[i], bf[j], acc[i][j], 0, 0, 0);
        __syncthreads();
    }

    int lrow = mt0 + wm * 64 + (lane >> 4) * 4;   // chunk-local output row base
    #pragma unroll
    for (int j = 0; j < 4; ++j) {
        int col = oc0 + wn * 64 + j * 16 + l15;
        float cbv = cb[col];
        float sp = 0.f, sq = 0.f;
        #pragma unroll
        for (int i = 0; i < 4; ++i) {
            #pragma unroll
            for (int q = 0; q < 4; ++q) {
                float v = acc[i][j][q] + cbv;
                if (STORE) C[(long)(lrow + i * 16 + q) * 768 + col] = f2bf(v);
                if (STATS) { sp += v; sq += v * v; }
            }
        }
        if (STATS) {
            sp += __shfl_xor(sp, 16); sp += __shfl_xor(sp, 32);
            sq += __shfl_xor(sq, 16); sq += __shfl_xor(sq, 32);
            if (lane < 16) {
                atomicAdd(&st2[col], sp);
                atomicAdd(&st2[768 + col], sq);
            }
        }
    }
}

__global__ void k_fin2(const float* __restrict__ st, const float* __restrict__ g,
        const float* __restrict__ bta, float* __restrict__ s2t2) {
    int c = blockIdx.x * 256 + threadIdx.x;
    if (c >= 768) return;
    float n = (float)NPIX;
    float mean = st[c] / n;
    float var  = st[768 + c] / n - mean * mean;
    float sc = g[c] * rsqrtf(var + 1e-5f);
    s2t2[c] = sc;
    s2t2[768 + c] = bta[c] - mean * sc;
}

// ---------------- pooling: grid (n_slices, 24) of 32-channel blocks ----------
__global__ __launch_bounds__(256) void k_pool2(const unsigned short* __restrict__ Cc,
        const int* __restrict__ seg, const float* __restrict__ s2t2,
        float* __restrict__ msum, float* __restrict__ mmax, int base_pix) {
    __shared__ float    ssum[S_ * 32];
    __shared__ unsigned smax[S_ * 32];
    int t = threadIdx.x;
    for (int i = t; i < S_ * 32; i += 256) { ssum[i] = 0.f; smax[i] = 0u; }
    __syncthreads();
    int ch0 = blockIdx.y * 32;
    int cl  = t & 31;                 // channel within block
    int ch  = ch0 + cl;
    int gp0 = base_pix + blockIdx.x * SL;
    float sc = s2t2[ch], sh = s2t2[768 + ch];
    const unsigned short* Cb = Cc + (long)blockIdx.x * SL * 768;   // chunk-local rows
    const int* sg = seg + gp0;
    for (int p = (t >> 5); p < SL; p += 8) {
        int s = sg[p];
        float v = sc * bf2f(Cb[(long)p * 768 + ch]) + sh;
        v = v > 0.f ? v : 0.f;
        atomicAdd(&ssum[s * 32 + cl], v);
        atomicMax(&smax[s * 32 + cl], __float_as_uint(v));
    }
    __syncthreads();
    int b = gp0 / HW;                 // exact: SL | HW
    for (int i = t; i < S_ * 32; i += 256) {
        int s = i >> 5; int cc = i & 31;
        long o = ((long)(b * S_ + s)) * 768 + ch0 + cc;
        atomicAdd(&msum[o], ssum[i]);
        atomicMax((unsigned*)&mmax[o], smax[i]);
    }
}

// ---------------- geometry: LDS-staged per-slice aggregation ----------------
__global__ void k_ginit(int* __restrict__ counts, int* __restrict__ bbox) {
    int i = blockIdx.x * 256 + threadIdx.x;
    if (i < B_ * S_) {
        counts[i] = 0;
        bbox[i * 4 + 0] = 1 << 29;  bbox[i * 4 + 1] = -1;
        bbox[i * 4 + 2] = 1 << 29;  bbox[i * 4 + 3] = -1;
    }
}

// grid: (28, 8) — slice s of batch b covers pixels [b*HW + s*1792, +1792)
__global__ __launch_bounds__(256) void k_geom3(const int* __restrict__ seg,
        int* __restrict__ counts, int* __restrict__ bbox) {
    __shared__ int cnt[S_], mnx[S_], mxx[S_], mny[S_], mxy[S_];
    int t = threadIdx.x;
    int b = blockIdx.y;
    int p0 = blockIdx.x * SL;         // within-batch pixel base
    for (int i = t; i < S_; i += 256) {
        cnt[i] = 0; mnx[i] = 1 << 29; mxx[i] = -1; mny[i] = 1 << 29; mxy[i] = -1;
    }
    __syncthreads();
    const int* sg = seg + (long)b * HW + p0;
    for (int p = t; p < SL; p += 256) {
        int s = sg[p];
        int gp = p0 + p;
        int y = gp / W_, x = gp - y * W_;
        atomicAdd(&cnt[s], 1);
        atomicMin(&mnx[s], x); atomicMax(&mxx[s], x);
        atomicMin(&mny[s], y); atomicMax(&mxy[s], y);
    }
    __syncthreads();
    for (int i = t; i < S_; i += 256) {
        if (cnt[i] == 0) continue;
        int k = b * S_ + i;
        atomicAdd(&counts[k], cnt[i]);
        atomicMin(&bbox[k * 4 + 0], mnx[i]); atomicMax(&bbox[k * 4 + 1], mxx[i]);
        atomicMin(&bbox[k * 4 + 2], mny[i]); atomicMax(&bbox[k * 4 + 3], mxy[i]);
    }
}

// ---------------- head: 7 tokens/block, coalesced transposed weights -> F32 out ----------
__global__ __launch_bounds__(256) void k_out3(
        const float* __restrict__ msum, const float* __restrict__ mmax,
        const int* __restrict__ counts, const int* __restrict__ bbox,
        const float* __restrict__ cent, const float* __restrict__ fwt,
        const float* __restrict__ swt, const float* __restrict__ fb,
        const float* __restrict__ sw1, const float* __restrict__ sb1,
        const float* __restrict__ sb2, const float* __restrict__ pw,
        const float* __restrict__ pb, float* __restrict__ out) {
    __shared__ float emb[7][1536];
    __shared__ float hid[7][768];
    int t = threadIdx.x;
    int gs0 = blockIdx.x * 7;         // 224 blocks * 7 = 1568 tokens
    #pragma unroll
    for (int si = 0; si < 7; ++si) {
        int gs = gs0 + si;
        int cnt = counts[gs];
        float cntf = (float)cnt;
        float inv = 1.f / fmaxf(cntf, 1.f);
        float bwf = 1.f, bhf = 1.f;
        if (cnt > 0) {
            bwf = (float)(bbox[gs * 4 + 1] - bbox[gs * 4 + 0] + 1);
            bhf = (float)(bbox[gs * 4 + 3] - bbox[gs * 4 + 2] + 1);
        }
        float asp = bwf / bhf;
        for (int k = t; k < 768; k += 256) {
            emb[si][k]       = msum[(long)gs * 768 + k] * inv;
            emb[si][768 + k] = mmax[(long)gs * 768 + k];
            float h = cntf * sw1[2 * k] + asp * sw1[2 * k + 1] + sb1[k];
            hid[si][k] = h > 0.f ? h : 0.f;
        }
    }
    __syncthreads();
    float accs[7][3];
    #pragma unroll
    for (int si = 0; si < 7; ++si) {
        int gs = gs0 + si;
        float cx = cent[gs * 2]     * (1.f / (float)W_);
        float cy = cent[gs * 2 + 1] * (1.f / (float)H_);
        #pragma unroll
        for (int rr = 0; rr < 3; ++rr) {
            int d = t + rr * 256;
            accs[si][rr] = fb[d] + sb2[d] + pb[d] + cx * pw[d * 2] + cy * pw[d * 2 + 1];
        }
    }
    #pragma unroll 2
    for (int k = 0; k < 1536; ++k) {
        const float* wr = fwt + (long)k * 768;
        float w0 = wr[t], w1 = wr[t + 256], w2 = wr[t + 512];
        #pragma unroll
        for (int si = 0; si < 7; ++si) {
            float e = emb[si][k];
            accs[si][0] += e * w0; accs[si][1] += e * w1; accs[si][2] += e * w2;
        }
    }
    #pragma unroll 2
    for (int k = 0; k < 768; ++k) {
        const float* wr = swt + (long)k * 768;
        float w0 = wr[t], w1 = wr[t + 256], w2 = wr[t + 512];
        #pragma unroll
        for (int si = 0; si < 7; ++si) {
            float e = hid[si][k];
            accs[si][0] += e * w0; accs[si][1] += e * w1; accs[si][2] += e * w2;
        }
    }
    #pragma unroll
    for (int si = 0; si < 7; ++si)
        #pragma unroll
        for (int rr = 0; rr < 3; ++rr)
            out[(long)(gs0 + si) * 768 + t + rr * 256] = accs[si][rr];
}

extern "C" void kernel_launch(void* const* d_in, const int* in_sizes, int n_in,
                              void* d_out, int out_size, void* d_ws, size_t ws_size,
                              hipStream_t stream) {
    const float* img  = (const float*)d_in[0];
    const int*   seg  = (const int*)  d_in[1];
    const float* cent = (const float*)d_in[2];
    const float* c1w  = (const float*)d_in[3];
    const float* c1b  = (const float*)d_in[4];
    const float* bn1g = (const float*)d_in[5];
    const float* bn1b = (const float*)d_in[6];
    const float* c2w  = (const float*)d_in[7];
    const float* c2b  = (const float*)d_in[8];
    const float* bn2g = (const float*)d_in[9];
    const float* bn2b = (const float*)d_in[10];
    const float* fw   = (const float*)d_in[11];
    const float* fbv  = (const float*)d_in[12];
    const float* pw   = (const float*)d_in[13];
    const float* pb   = (const float*)d_in[14];
    const float* sw1  = (const float*)d_in[15];
    const float* sb1  = (const float*)d_in[16];
    const float* sw2  = (const float*)d_in[17];
    const float* sb2  = (const float*)d_in[18];

    char* base = (char*)d_ws;
    size_t used = 0;
    auto alloc = [&](size_t bytes) {
        char* p = base + used;
        used += (bytes + 255) & ~(size_t)255;
        return p;
    };
    unsigned short* x2 = (unsigned short*)alloc((size_t)NPIX * 64 * 2);     // 51.4 MB
    unsigned short* Bm = (unsigned short*)alloc((size_t)768 * 576 * 2);     // 0.88 MB
    float* fwt  = (float*)alloc((size_t)1536 * 768 * 4);                    // 4.72 MB
    float* swt  = (float*)alloc((size_t)768 * 768 * 4);                     // 2.36 MB
    float* st1  = (float*)alloc(128 * 4);
    float* s1t1 = (float*)alloc(128 * 4);
    float* st2  = (float*)alloc(1536 * 4);
    float* s2t2 = (float*)alloc(1536 * 4);
    float* msum = (float*)alloc((size_t)B_ * S_ * 768 * 4);                 // 4.82 MB
    float* mmax = (float*)alloc((size_t)B_ * S_ * 768 * 4);                 // 4.82 MB
    int* counts = (int*)alloc(B_ * S_ * 4);
    int* bbox   = (int*)alloc(B_ * S_ * 16);
    const size_t UNIT_BYTES = (size_t)SL * 768 * 2;   // 2.75 MB per slice
    unsigned short* Cc = (unsigned short*)(base + used);
    long units = 0;
    if (ws_size > used) units = (long)((ws_size - used) / UNIT_BYTES);
    if (units > NSL) units = NSL;
    if (units < 1)  units = 1;

    hipMemsetAsync(st1, 0, 128 * 4, stream);
    hipMemsetAsync(st2, 0, 1536 * 4, stream);
    hipMemsetAsync(msum, 0, (size_t)B_ * S_ * 768 * 4, stream);
    hipMemsetAsync(mmax, 0, (size_t)B_ * S_ * 768 * 4, stream);

    k_conv1s<<<2048, 256, 0, stream>>>(img, c1w, c1b, st1);
    k_fin1<<<1, 64, 0, stream>>>(st1, bn1g, bn1b, s1t1);
    k_conv1a<<<NPIX / 4, 256, 0, stream>>>(img, c1w, c1b, s1t1, x2);
    k_prep<<<(1536 * 768) / 256, 256, 0, stream>>>(c2w, fw, sw2, Bm, fwt, swt);

    if (units >= NSL) {
        dim3 g2(NPIX / 128, 6);
        k_conv2<1, 1><<<g2, 256, 0, stream>>>(x2, Bm, c2b, Cc, st2, 0);
        k_fin2<<<3, 256, 0, stream>>>(st2, bn2g, bn2b, s2t2);
        dim3 gp(NSL, 24);
        k_pool2<<<gp, 256, 0, stream>>>(Cc, seg, s2t2, msum, mmax, 0);
    } else {
        dim3 g2(NPIX / 128, 6);
        k_conv2<0, 1><<<g2, 256, 0, stream>>>(x2, Bm, c2b, Cc, st2, 0);
        k_fin2<<<3, 256, 0, stream>>>(st2, bn2g, bn2b, s2t2);
        for (long u = 0; u < NSL; u += units) {
            long nu = (NSL - u < units) ? (NSL - u) : units;
            dim3 gc((unsigned)(nu * (SL / 128)), 6);
            k_conv2<1, 0><<<gc, 256, 0, stream>>>(x2, Bm, c2b, Cc, st2, (int)(u * SL));
            dim3 gp((unsigned)nu, 24);
            k_pool2<<<gp, 256, 0, stream>>>(Cc, seg, s2t2, msum, mmax, (int)(u * SL));
        }
    }

    k_ginit<<<(B_ * S_ + 255) / 256, 256, 0, stream>>>(counts, bbox);
    dim3 gg(28, 8);
    k_geom3<<<gg, 256, 0, stream>>>(seg, counts, bbox);
    k_out3<<<224, 256, 0, stream>>>(msum, mmax, counts, bbox, cent, fwt, swt,
                                    fbv, sw1, sb1, sb2, pw, pb,
                                    (float*)d_out);
    (void)in_sizes; (void)n_in; (void)out_size;
}

// Round 9
// 3609.987 us; speedup vs baseline: 1.8080x; 1.1167x over previous
//
#include <hip/hip_runtime.h>
#include <hip/hip_bf16.h>

typedef __attribute__((ext_vector_type(8))) short s16x8;
typedef __attribute__((ext_vector_type(4))) float f32x4;

#define B_    8
#define H_    224
#define W_    224
#define S_    196
#define D_    768
#define HW    50176          // 224*224
#define NPIX  401408         // B_*HW
#define SL    1792           // geom slice: 1792*28 = HW exactly

__device__ inline float bf2f(unsigned short u) {
    return __uint_as_float(((unsigned)u) << 16);
}
__device__ inline unsigned short f2bf(float f) {
    unsigned u = __float_as_uint(f);
    u = (u + 0x7FFFu + ((u >> 16) & 1u)) >> 16;
    return (unsigned short)u;
}

// ---------------- conv1 pass 1: raw conv -> BN1 batch stats only ----------------
__global__ __launch_bounds__(256) void k_conv1s(const float* __restrict__ img,
        const float* __restrict__ w, const float* __restrict__ bias,
        float* __restrict__ st) {
    __shared__ float lw[64 * 27];
    __shared__ float ls[256], lq[256];
    int t = threadIdx.x;
    for (int i = t; i < 64 * 27; i += 256) lw[i] = w[i];
    __syncthreads();
    int oc = t & 63;
    float bv = bias[oc];
    float s = 0.f, q = 0.f;
    for (int pg = blockIdx.x; pg < NPIX / 4; pg += 2048) {
        int p = pg * 4 + (t >> 6);
        int b = p / HW; int rem = p - b * HW;
        int y = rem / W_; int x = rem - y * W_;
        const float* ib = img + (long)b * 3 * HW;
        float acc = bv;
        #pragma unroll
        for (int ic = 0; ic < 3; ++ic) {
            #pragma unroll
            for (int ky = 0; ky < 3; ++ky) {
                int yy = y + ky - 1;
                if (yy < 0 || yy >= H_) continue;
                #pragma unroll
                for (int kx = 0; kx < 3; ++kx) {
                    int xx = x + kx - 1;
                    if (xx < 0 || xx >= W_) continue;
                    acc += ib[(ic * H_ + yy) * W_ + xx] * lw[oc * 27 + ic * 9 + ky * 3 + kx];
                }
            }
        }
        s += acc; q += acc * acc;
    }
    ls[t] = s; lq[t] = q;
    __syncthreads();
    if (t < 64) {
        atomicAdd(&st[t],      ls[t] + ls[t + 64] + ls[t + 128] + ls[t + 192]);
        atomicAdd(&st[64 + t], lq[t] + lq[t + 64] + lq[t + 128] + lq[t + 192]);
    }
}

__global__ void k_fin1(const float* __restrict__ st, const float* __restrict__ g,
        const float* __restrict__ bta, float* __restrict__ s1t1) {
    int c = threadIdx.x;
    if (c >= 64) return;
    float n = (float)NPIX;
    float mean = st[c] / n;
    float var  = st[64 + c] / n - mean * mean;
    float sc = g[c] * rsqrtf(var + 1e-5f);
    s1t1[c] = sc;
    s1t1[64 + c] = bta[c] - mean * sc;
}

// ---------------- conv1 pass 2: recompute + BN1 + ReLU -> UNPADDED NHWC bf16 ----------------
__global__ __launch_bounds__(256) void k_conv1a(const float* __restrict__ img,
        const float* __restrict__ w, const float* __restrict__ bias,
        const float* __restrict__ s1t1, unsigned short* __restrict__ x2) {
    __shared__ float lw[64 * 27];
    int t = threadIdx.x;
    for (int i = t; i < 64 * 27; i += 256) lw[i] = w[i];
    __syncthreads();
    int oc = t & 63;
    int p  = blockIdx.x * 4 + (t >> 6);
    int b = p / HW; int rem = p - b * HW;
    int y = rem / W_; int x = rem - y * W_;
    const float* ib = img + (long)b * 3 * HW;
    float acc = bias[oc];
    #pragma unroll
    for (int ic = 0; ic < 3; ++ic) {
        #pragma unroll
        for (int ky = 0; ky < 3; ++ky) {
            int yy = y + ky - 1;
            if (yy < 0 || yy >= H_) continue;
            #pragma unroll
            for (int kx = 0; kx < 3; ++kx) {
                int xx = x + kx - 1;
                if (xx < 0 || xx >= W_) continue;
                acc += ib[(ic * H_ + yy) * W_ + xx] * lw[oc * 27 + ic * 9 + ky * 3 + kx];
            }
        }
    }
    float v = s1t1[oc] * acc + s1t1[64 + oc];
    v = v > 0.f ? v : 0.f;
    x2[(long)p * 64 + oc] = f2bf(v);
}

// ---------------- weight prep: Bm [768][576] bf16 + transposed f32 head weights ----------
__global__ __launch_bounds__(256) void k_prep(const float* __restrict__ w2,
        const float* __restrict__ fw, const float* __restrict__ sw2,
        unsigned short* __restrict__ Bm, float* __restrict__ fwt, float* __restrict__ swt) {
    int i = blockIdx.x * 256 + threadIdx.x;
    if (i < 768 * 576) {
        int oc = i / 576, k = i - oc * 576;
        int tap = k >> 6, ic = k & 63;
        Bm[i] = f2bf(w2[(oc * 64 + ic) * 9 + tap]);
    }
    if (i < 1536 * 768) {          // fwt[k][d] = fw[d][k]
        int k = i / 768, d = i - k * 768;
        fwt[i] = fw[(long)d * 1536 + k];
    }
    if (i < 768 * 768) {           // swt[k][d] = sw2[d][k]
        int k = i / 768, d = i - k * 768;
        swt[i] = sw2[(long)d * 768 + k];
    }
}

// ---------------- conv2 implicit GEMM, 128x256 tile, swizzled LDS ----------------
// POOL=0: BN2 batch stats (pre-ReLU sum/sumsq per channel) -> st2 atomics.
// POOL=1: BN2 apply + ReLU + segment sum/max pooling -> msum/mmax atomics.
template<int POOL>
__global__ __launch_bounds__(256, 2) void k_conv2b(const unsigned short* __restrict__ x2,
        const unsigned short* __restrict__ Bm, const float* __restrict__ cb,
        const int* __restrict__ seg, const float* __restrict__ s2t2,
        float* __restrict__ st2, float* __restrict__ msum, unsigned* __restrict__ mmax) {
    __shared__ short lA[128 * 32];
    __shared__ short lB[256 * 32];
    __shared__ int lsg[128];
    int t = threadIdx.x;
    int m0  = blockIdx.x * 128;
    int oc0 = blockIdx.y * 256;

    // A staging: thread covers 32B (2 swizzled 16B slots) of one A row
    int r   = t >> 1;
    int s0  = (t & 1) * 2;            // base slot (0 or 2)
    int swa = (r >> 1) & 3;
    int m = m0 + r;
    int b = m / HW; int rem = m - b * HW;
    int y = rem / W_; int x = rem - y * W_;
    const unsigned short* Pb = x2 + (long)b * HW * 64;
    // B staging: thread covers full 64B of B row (oc0 + t)
    const unsigned short* Q = Bm + (long)(oc0 + t) * 576;
    int swb = (t >> 1) & 3;

    int lane = t & 63;
    int w = t >> 6;
    int wm = w >> 1, wn = w & 1;
    int l15 = lane & 15;
    int slot = lane >> 4;

    f32x4 acc[2][4][4];
    #pragma unroll
    for (int tl = 0; tl < 2; ++tl)
        #pragma unroll
        for (int i = 0; i < 4; ++i)
            #pragma unroll
            for (int j = 0; j < 4; ++j) acc[tl][i][j] = (f32x4){0.f, 0.f, 0.f, 0.f};

    for (int s = 0; s < 18; ++s) {
        int tap = s >> 1;
        int ty = tap / 3, tx = tap - ty * 3;
        int yy = y + 2 * ty - 2;
        int xx = x + 2 * tx - 2;
        float4 a0 = {0.f, 0.f, 0.f, 0.f}, a1 = {0.f, 0.f, 0.f, 0.f};
        if ((unsigned)yy < (unsigned)H_ && (unsigned)xx < (unsigned)W_) {
            const unsigned short* src = Pb + ((long)yy * W_ + xx) * 64 + (s & 1) * 32 + s0 * 8;
            a0 = *(const float4*)src;
            a1 = *(const float4*)(src + 8);
        }
        const unsigned short* qs = Q + s * 32;
        float4 b0 = *(const float4*)(qs);
        float4 b1 = *(const float4*)(qs + 8);
        float4 b2 = *(const float4*)(qs + 16);
        float4 b3 = *(const float4*)(qs + 24);
        *(float4*)&lA[r * 32 + ((s0     ^ swa) * 8)] = a0;
        *(float4*)&lA[r * 32 + (((s0+1) ^ swa) * 8)] = a1;
        *(float4*)&lB[t * 32 + ((0 ^ swb) * 8)] = b0;
        *(float4*)&lB[t * 32 + ((1 ^ swb) * 8)] = b1;
        *(float4*)&lB[t * 32 + ((2 ^ swb) * 8)] = b2;
        *(float4*)&lB[t * 32 + ((3 ^ swb) * 8)] = b3;
        __syncthreads();
        s16x8 af[4], bf[2][4];
        #pragma unroll
        for (int i = 0; i < 4; ++i) {
            int arow = wm * 64 + i * 16 + l15;
            af[i] = *(const s16x8*)&lA[arow * 32 + ((slot ^ ((arow >> 1) & 3)) * 8)];
        }
        #pragma unroll
        for (int tl = 0; tl < 2; ++tl)
            #pragma unroll
            for (int j = 0; j < 4; ++j) {
                int brow = tl * 128 + wn * 64 + j * 16 + l15;
                bf[tl][j] = *(const s16x8*)&lB[brow * 32 + ((slot ^ ((brow >> 1) & 3)) * 8)];
            }
        #pragma unroll
        for (int tl = 0; tl < 2; ++tl)
            #pragma unroll
            for (int i = 0; i < 4; ++i)
                #pragma unroll
                for (int j = 0; j < 4; ++j)
                    acc[tl][i][j] = __builtin_amdgcn_mfma_f32_16x16x32_bf16(af[i], bf[tl][j], acc[tl][i][j], 0, 0, 0);
        __syncthreads();
    }

    if (POOL) {
        if (t < 128) {
            int mm = m0 + t;
            lsg[t] = (mm / HW) * S_ + seg[mm];
        }
        __syncthreads();
    }

    #pragma unroll
    for (int tl = 0; tl < 2; ++tl) {
        #pragma unroll
        for (int j = 0; j < 4; ++j) {
            int col = oc0 + tl * 128 + wn * 64 + j * 16 + l15;
            float cbv = cb[col];
            if (POOL) {
                float sc = s2t2[col], sh = s2t2[768 + col];
                #pragma unroll
                for (int i = 0; i < 4; ++i) {
                    #pragma unroll
                    for (int q = 0; q < 4; ++q) {
                        float v2 = sc * (acc[tl][i][j][q] + cbv) + sh;
                        if (v2 > 0.f) {
                            int gsi = lsg[wm * 64 + i * 16 + slot * 4 + q];
                            long o = (long)gsi * 768 + col;
                            atomicAdd(&msum[o], v2);
                            atomicMax(&mmax[o], __float_as_uint(v2));
                        }
                    }
                }
            } else {
                float sp = 0.f, sq = 0.f;
                #pragma unroll
                for (int i = 0; i < 4; ++i) {
                    #pragma unroll
                    for (int q = 0; q < 4; ++q) {
                        float v = acc[tl][i][j][q] + cbv;
                        sp += v; sq += v * v;
                    }
                }
                sp += __shfl_xor(sp, 16); sp += __shfl_xor(sp, 32);
                sq += __shfl_xor(sq, 16); sq += __shfl_xor(sq, 32);
                if (lane < 16) {
                    atomicAdd(&st2[col], sp);
                    atomicAdd(&st2[768 + col], sq);
                }
            }
        }
    }
}

__global__ void k_fin2(const float* __restrict__ st, const float* __restrict__ g,
        const float* __restrict__ bta, float* __restrict__ s2t2) {
    int c = blockIdx.x * 256 + threadIdx.x;
    if (c >= 768) return;
    float n = (float)NPIX;
    float mean = st[c] / n;
    float var  = st[768 + c] / n - mean * mean;
    float sc = g[c] * rsqrtf(var + 1e-5f);
    s2t2[c] = sc;
    s2t2[768 + c] = bta[c] - mean * sc;
}

// ---------------- geometry: LDS-staged per-slice aggregation ----------------
__global__ void k_ginit(int* __restrict__ counts, int* __restrict__ bbox) {
    int i = blockIdx.x * 256 + threadIdx.x;
    if (i < B_ * S_) {
        counts[i] = 0;
        bbox[i * 4 + 0] = 1 << 29;  bbox[i * 4 + 1] = -1;
        bbox[i * 4 + 2] = 1 << 29;  bbox[i * 4 + 3] = -1;
    }
}

__global__ __launch_bounds__(256) void k_geom3(const int* __restrict__ seg,
        int* __restrict__ counts, int* __restrict__ bbox) {
    __shared__ int cnt[S_], mnx[S_], mxx[S_], mny[S_], mxy[S_];
    int t = threadIdx.x;
    int b = blockIdx.y;
    int p0 = blockIdx.x * SL;
    for (int i = t; i < S_; i += 256) {
        cnt[i] = 0; mnx[i] = 1 << 29; mxx[i] = -1; mny[i] = 1 << 29; mxy[i] = -1;
    }
    __syncthreads();
    const int* sg = seg + (long)b * HW + p0;
    for (int p = t; p < SL; p += 256) {
        int s = sg[p];
        int gp = p0 + p;
        int y = gp / W_, x = gp - y * W_;
        atomicAdd(&cnt[s], 1);
        atomicMin(&mnx[s], x); atomicMax(&mxx[s], x);
        atomicMin(&mny[s], y); atomicMax(&mxy[s], y);
    }
    __syncthreads();
    for (int i = t; i < S_; i += 256) {
        if (cnt[i] == 0) continue;
        int k = b * S_ + i;
        atomicAdd(&counts[k], cnt[i]);
        atomicMin(&bbox[k * 4 + 0], mnx[i]); atomicMax(&bbox[k * 4 + 1], mxx[i]);
        atomicMin(&bbox[k * 4 + 2], mny[i]); atomicMax(&bbox[k * 4 + 3], mxy[i]);
    }
}

// ---------------- head: 7 tokens/block, coalesced transposed weights -> F32 out ----------
__global__ __launch_bounds__(256) void k_out3(
        const float* __restrict__ msum, const float* __restrict__ mmax,
        const int* __restrict__ counts, const int* __restrict__ bbox,
        const float* __restrict__ cent, const float* __restrict__ fwt,
        const float* __restrict__ swt, const float* __restrict__ fb,
        const float* __restrict__ sw1, const float* __restrict__ sb1,
        const float* __restrict__ sb2, const float* __restrict__ pw,
        const float* __restrict__ pb, float* __restrict__ out) {
    __shared__ float emb[7][1536];
    __shared__ float hid[7][768];
    int t = threadIdx.x;
    int gs0 = blockIdx.x * 7;
    #pragma unroll
    for (int si = 0; si < 7; ++si) {
        int gs = gs0 + si;
        int cnt = counts[gs];
        float cntf = (float)cnt;
        float inv = 1.f / fmaxf(cntf, 1.f);
        float bwf = 1.f, bhf = 1.f;
        if (cnt > 0) {
            bwf = (float)(bbox[gs * 4 + 1] - bbox[gs * 4 + 0] + 1);
            bhf = (float)(bbox[gs * 4 + 3] - bbox[gs * 4 + 2] + 1);
        }
        float asp = bwf / bhf;
        for (int k = t; k < 768; k += 256) {
            emb[si][k]       = msum[(long)gs * 768 + k] * inv;
            emb[si][768 + k] = mmax[(long)gs * 768 + k];
            float h = cntf * sw1[2 * k] + asp * sw1[2 * k + 1] + sb1[k];
            hid[si][k] = h > 0.f ? h : 0.f;
        }
    }
    __syncthreads();
    float accs[7][3];
    #pragma unroll
    for (int si = 0; si < 7; ++si) {
        int gs = gs0 + si;
        float cx = cent[gs * 2]     * (1.f / (float)W_);
        float cy = cent[gs * 2 + 1] * (1.f / (float)H_);
        #pragma unroll
        for (int rr = 0; rr < 3; ++rr) {
            int d = t + rr * 256;
            accs[si][rr] = fb[d] + sb2[d] + pb[d] + cx * pw[d * 2] + cy * pw[d * 2 + 1];
        }
    }
    #pragma unroll 2
    for (int k = 0; k < 1536; ++k) {
        const float* wr = fwt + (long)k * 768;
        float w0 = wr[t], w1 = wr[t + 256], w2 = wr[t + 512];
        #pragma unroll
        for (int si = 0; si < 7; ++si) {
            float e = emb[si][k];
            accs[si][0] += e * w0; accs[si][1] += e * w1; accs[si][2] += e * w2;
        }
    }
    #pragma unroll 2
    for (int k = 0; k < 768; ++k) {
        const float* wr = swt + (long)k * 768;
        float w0 = wr[t], w1 = wr[t + 256], w2 = wr[t + 512];
        #pragma unroll
        for (int si = 0; si < 7; ++si) {
            float e = hid[si][k];
            accs[si][0] += e * w0; accs[si][1] += e * w1; accs[si][2] += e * w2;
        }
    }
    #pragma unroll
    for (int si = 0; si < 7; ++si)
        #pragma unroll
        for (int rr = 0; rr < 3; ++rr)
            out[(long)(gs0 + si) * 768 + t + rr * 256] = accs[si][rr];
}

extern "C" void kernel_launch(void* const* d_in, const int* in_sizes, int n_in,
                              void* d_out, int out_size, void* d_ws, size_t ws_size,
                              hipStream_t stream) {
    const float* img  = (const float*)d_in[0];
    const int*   seg  = (const int*)  d_in[1];
    const float* cent = (const float*)d_in[2];
    const float* c1w  = (const float*)d_in[3];
    const float* c1b  = (const float*)d_in[4];
    const float* bn1g = (const float*)d_in[5];
    const float* bn1b = (const float*)d_in[6];
    const float* c2w  = (const float*)d_in[7];
    const float* c2b  = (const float*)d_in[8];
    const float* bn2g = (const float*)d_in[9];
    const float* bn2b = (const float*)d_in[10];
    const float* fw   = (const float*)d_in[11];
    const float* fbv  = (const float*)d_in[12];
    const float* pw   = (const float*)d_in[13];
    const float* pb   = (const float*)d_in[14];
    const float* sw1  = (const float*)d_in[15];
    const float* sb1  = (const float*)d_in[16];
    const float* sw2  = (const float*)d_in[17];
    const float* sb2  = (const float*)d_in[18];

    char* base = (char*)d_ws;
    size_t used = 0;
    auto alloc = [&](size_t bytes) {
        char* p = base + used;
        used += (bytes + 255) & ~(size_t)255;
        return p;
    };
    unsigned short* x2 = (unsigned short*)alloc((size_t)NPIX * 64 * 2);     // 51.4 MB
    unsigned short* Bm = (unsigned short*)alloc((size_t)768 * 576 * 2);     // 0.88 MB
    float* fwt  = (float*)alloc((size_t)1536 * 768 * 4);                    // 4.72 MB
    float* swt  = (float*)alloc((size_t)768 * 768 * 4);                     // 2.36 MB
    float* st1  = (float*)alloc(128 * 4);
    float* s1t1 = (float*)alloc(128 * 4);
    float* st2  = (float*)alloc(1536 * 4);
    float* s2t2 = (float*)alloc(1536 * 4);
    float* msum = (float*)alloc((size_t)B_ * S_ * 768 * 4);                 // 4.82 MB
    unsigned* mmax = (unsigned*)alloc((size_t)B_ * S_ * 768 * 4);           // 4.82 MB
    int* counts = (int*)alloc(B_ * S_ * 4);
    int* bbox   = (int*)alloc(B_ * S_ * 16);
    // total ~69.5 MB, no conv2-output buffer needed (pool fused into GEMM epilogue)

    hipMemsetAsync(st1, 0, 128 * 4, stream);
    hipMemsetAsync(st2, 0, 1536 * 4, stream);
    hipMemsetAsync(msum, 0, (size_t)B_ * S_ * 768 * 4, stream);
    hipMemsetAsync(mmax, 0, (size_t)B_ * S_ * 768 * 4, stream);

    k_conv1s<<<2048, 256, 0, stream>>>(img, c1w, c1b, st1);
    k_fin1<<<1, 64, 0, stream>>>(st1, bn1g, bn1b, s1t1);
    k_conv1a<<<NPIX / 4, 256, 0, stream>>>(img, c1w, c1b, s1t1, x2);
    k_prep<<<(1536 * 768) / 256, 256, 0, stream>>>(c2w, fw, sw2, Bm, fwt, swt);

    dim3 g2(NPIX / 128, 3);
    k_conv2b<0><<<g2, 256, 0, stream>>>(x2, Bm, c2b, seg, s2t2, st2, msum, mmax);
    k_fin2<<<3, 256, 0, stream>>>(st2, bn2g, bn2b, s2t2);
    k_conv2b<1><<<g2, 256, 0, stream>>>(x2, Bm, c2b, seg, s2t2, st2, msum, mmax);

    k_ginit<<<(B_ * S_ + 255) / 256, 256, 0, stream>>>(counts, bbox);
    dim3 gg(28, 8);
    k_geom3<<<gg, 256, 0, stream>>>(seg, counts, bbox);
    k_out3<<<224, 256, 0, stream>>>(msum, (const float*)mmax, counts, bbox, cent, fwt, swt,
                                    fbv, sw1, sb1, sb2, pw, pb,
                                    (float*)d_out);
    (void)in_sizes; (void)n_in; (void)out_size; (void)ws_size;
}